// Round 1
// baseline (89.318 us; speedup 1.0000x reference)
//
#include <hip/hip_runtime.h>
#include <math.h>

#define THREADS 256

__device__ __forceinline__ void box2corners(float x, float y, float w, float h, float a,
                                            float* cx, float* cy) {
    const float tx[4] = {0.5f, -0.5f, -0.5f, 0.5f};
    const float ty[4] = {0.5f, 0.5f, -0.5f, -0.5f};
    float c = cosf(a), s = sinf(a);
#pragma unroll
    for (int k = 0; k < 4; k++) {
        float xo = w * tx[k], yo = h * ty[k];
        cx[k] = x + c * xo - s * yo;
        cy[k] = y + s * xo + c * yo;
    }
}

// returns 4-bit mask: corner k of (cx,cy) inside oriented box (ox,oy)
__device__ __forceinline__ unsigned corners_in_box(const float* cx, const float* cy,
                                                   const float* ox, const float* oy) {
    float abx = ox[1] - ox[0], aby = oy[1] - oy[0];
    float adx = ox[3] - ox[0], ady = oy[3] - oy[0];
    float nab = abx * abx + aby * aby;
    float nad = adx * adx + ady * ady;
    unsigned m = 0;
#pragma unroll
    for (int k = 0; k < 4; k++) {
        float amx = cx[k] - ox[0], amy = cy[k] - oy[0];
        float qab = (abx * amx + aby * amy) / nab;
        float qad = (adx * amx + ady * amy) / nad;
        bool c = (qab > -1e-6f) && (qab < 1.0f + 1e-6f) &&
                 (qad > -1e-6f) && (qad < 1.0f + 1e-6f);
        m |= ((unsigned)c) << k;
    }
    return m;
}

__global__ void __launch_bounds__(THREADS) iou3d_kernel(
    const float* __restrict__ pred, const float* __restrict__ tgt,
    const float* __restrict__ wgt, float* __restrict__ partial, int N) {
    int n = blockIdx.x * THREADS + threadIdx.x;
    float loss = 0.0f;
    if (n < N) {
        float p[7], t[7];
#pragma unroll
        for (int k = 0; k < 7; k++) {
            p[k] = pred[(size_t)n * 7 + k];
            float tv = tgt[(size_t)n * 7 + k];
            t[k] = isnan(tv) ? p[k] : tv;
        }
        float c1x[4], c1y[4], c2x[4], c2y[4];
        box2corners(p[0], p[1], p[3], p[4], p[6], c1x, c1y);
        box2corners(t[0], t[1], t[3], t[4], t[6], c2x, c2y);

        float vx[24], vy[24], ang[24];
        unsigned vm = 0;
        unsigned m12 = corners_in_box(c1x, c1y, c2x, c2y);
        unsigned m21 = corners_in_box(c2x, c2y, c1x, c1y);
#pragma unroll
        for (int k = 0; k < 4; k++) { vx[k] = c1x[k]; vy[k] = c1y[k]; }
#pragma unroll
        for (int k = 0; k < 4; k++) { vx[4 + k] = c2x[k]; vy[4 + k] = c2y[k]; }
        vm = m12 | (m21 << 4);

        // 16 edge-edge intersections; slot 8 + e1*4 + e2 (line1-major like reshape)
#pragma unroll
        for (int e1 = 0; e1 < 4; e1++) {
            float x1 = c1x[e1], y1 = c1y[e1];
            float x2 = c1x[(e1 + 1) & 3], y2 = c1y[(e1 + 1) & 3];
#pragma unroll
            for (int e2 = 0; e2 < 4; e2++) {
                float x3 = c2x[e2], y3 = c2y[e2];
                float x4 = c2x[(e2 + 1) & 3], y4 = c2y[(e2 + 1) & 3];
                float num = (y4 - y3) * (x2 - x1) - (x4 - x3) * (y2 - y1);
                float den_t = (x4 - x3) * (y1 - y3) - (y4 - y3) * (x1 - x3);
                float den_u = (x2 - x1) * (y1 - y3) - (y2 - y1) * (x1 - x3);
                bool nz = (num != 0.0f);
                float tt = nz ? den_t / num : -1.0f;
                float uu = nz ? -den_u / num : -1.0f;
                bool mk = (tt > 0.0f) && (tt < 1.0f) && (uu > 0.0f) && (uu < 1.0f);
                int idx = 8 + e1 * 4 + e2;
                vx[idx] = mk ? x1 + tt * (x2 - x1) : 0.0f;
                vy[idx] = mk ? y1 + tt * (y2 - y1) : 0.0f;
                vm |= ((unsigned)mk) << idx;
            }
        }

        // centroid of valid vertices
        float sx = 0.0f, sy = 0.0f;
        int nv = 0;
#pragma unroll
        for (int k = 0; k < 24; k++) {
            bool v = (vm >> k) & 1u;
            sx += v ? vx[k] : 0.0f;
            sy += v ? vy[k] : 0.0f;
            nv += (int)v;
        }
        float den = fmaxf((float)nv, 1.0f);
        float mx = sx / den, my = sy / den;

#pragma unroll
        for (int k = 0; k < 24; k++) {
            bool v = (vm >> k) & 1u;
            ang[k] = v ? atan2f(vy[k] - my, vx[k] - mx) : 1e6f;
        }

        // global min key (angle, then index) among valid — the wrap target
        float ga = 1e30f, gx = 0.0f, gy = 0.0f;
#pragma unroll
        for (int j = 0; j < 24; j++) {
            bool v = (vm >> j) & 1u;
            bool upd = v && (ang[j] < ga);   // strict < keeps lowest index on ties
            ga = upd ? ang[j] : ga;
            gx = upd ? vx[j] : gx;
            gy = upd ? vy[j] : gy;
        }

        // shoelace over stable-angle-sorted cycle via successor scan
        float area2 = 0.0f;
#pragma unroll
        for (int i = 0; i < 24; i++) {
            if (!((vm >> i) & 1u)) continue;
            float ai = ang[i];
            float ba = 1e30f;
            int bi = 64;
            float bx = gx, by = gy;   // default: wrap to global min
#pragma unroll
            for (int j = 0; j < 24; j++) {
                if (j == i) continue;
                bool v = (vm >> j) & 1u;
                bool gt = (ang[j] > ai) || ((ang[j] == ai) && (j > i));
                bool better = (ang[j] < ba) || ((ang[j] == ba) && (j < bi));
                bool upd = v && gt && better;
                ba = upd ? ang[j] : ba;
                bi = upd ? j : bi;
                bx = upd ? vx[j] : bx;
                by = upd ? vy[j] : by;
            }
            area2 += vx[i] * by - bx * vy[i];
        }
        float inter2d = 0.5f * fabsf(area2);

        float zmax1 = p[2] + p[5] * 0.5f, zmin1 = p[2] - p[5] * 0.5f;
        float zmax2 = t[2] + t[5] * 0.5f, zmin2 = t[2] - t[5] * 0.5f;
        float zov = fmaxf(fminf(zmax1, zmax2) - fmaxf(zmin1, zmin2), 0.0f);
        float inter3d = inter2d * zov;
        float v1 = p[3] * p[4] * p[5];
        float v2 = t[3] * t[4] * t[5];
        float uni = v1 + v2 - inter3d;
        float iou = inter3d / uni;
        loss = (1.0f - iou) * wgt[n];
    }

    // deterministic block reduction: wave shuffle tree then LDS
#pragma unroll
    for (int off = 32; off > 0; off >>= 1) loss += __shfl_down(loss, off, 64);
    __shared__ float sm[THREADS / 64];
    int lane = threadIdx.x & 63, wv = threadIdx.x >> 6;
    if (lane == 0) sm[wv] = loss;
    __syncthreads();
    if (threadIdx.x == 0) {
        float s = 0.0f;
#pragma unroll
        for (int w = 0; w < THREADS / 64; w++) s += sm[w];
        partial[blockIdx.x] = s;
    }
}

__global__ void __launch_bounds__(256) reduce_kernel(const float* __restrict__ partial,
                                                     int nb, float* __restrict__ out, int N) {
    __shared__ float sm[256];
    float s = 0.0f;
    for (int i = threadIdx.x; i < nb; i += 256) s += partial[i];
    sm[threadIdx.x] = s;
    __syncthreads();
    for (int off = 128; off > 0; off >>= 1) {
        if (threadIdx.x < off) sm[threadIdx.x] += sm[threadIdx.x + off];
        __syncthreads();
    }
    if (threadIdx.x == 0) out[0] = sm[0] / (float)N;
}

extern "C" void kernel_launch(void* const* d_in, const int* in_sizes, int n_in,
                              void* d_out, int out_size, void* d_ws, size_t ws_size,
                              hipStream_t stream) {
    const float* pred = (const float*)d_in[0];
    const float* tgt  = (const float*)d_in[1];
    const float* wgt  = (const float*)d_in[2];
    int N = in_sizes[2];  // weight element count = number of boxes
    int nb = (N + THREADS - 1) / THREADS;
    float* partial = (float*)d_ws;
    iou3d_kernel<<<nb, THREADS, 0, stream>>>(pred, tgt, wgt, partial, N);
    reduce_kernel<<<1, 256, 0, stream>>>(partial, nb, (float*)d_out, N);
}

// Round 2
// 38.450 us; speedup vs baseline: 2.3230x; 2.3230x over previous
//
#include <hip/hip_runtime.h>
#include <math.h>

#define THREADS 256

__device__ __forceinline__ float prcp(float x) { return __builtin_amdgcn_rcpf(x); }

__global__ void __launch_bounds__(THREADS) iou3d_kernel(
    const float* __restrict__ pred, const float* __restrict__ tgt,
    const float* __restrict__ wgt, float* __restrict__ partial, int N) {
    int n = blockIdx.x * THREADS + threadIdx.x;
    float loss = 0.0f;
    if (n < N) {
        float p[7], t[7];
#pragma unroll
        for (int k = 0; k < 7; k++) {
            p[k] = pred[(size_t)n * 7 + k];
            float tv = tgt[(size_t)n * 7 + k];
            t[k] = (tv != tv) ? p[k] : tv;
        }
        // ---- corners ----
        const float txc[4] = {0.5f, -0.5f, -0.5f, 0.5f};
        const float tyc[4] = {0.5f, 0.5f, -0.5f, -0.5f};
        float s1, c1, s2, c2;
        __sincosf(p[6], &s1, &c1);
        __sincosf(t[6], &s2, &c2);
        float c1x[4], c1y[4], c2x[4], c2y[4];
#pragma unroll
        for (int k = 0; k < 4; k++) {
            float xo = p[3] * txc[k], yo = p[4] * tyc[k];
            c1x[k] = p[0] + c1 * xo - s1 * yo;
            c1y[k] = p[1] + s1 * xo + c1 * yo;
            xo = t[3] * txc[k]; yo = t[4] * tyc[k];
            c2x[k] = t[0] + c2 * xo - s2 * yo;
            c2y[k] = t[1] + s2 * xo + c2 * yo;
        }

        float vx[24], vy[24];
        unsigned vm = 0;
#pragma unroll
        for (int k = 0; k < 4; k++) { vx[k] = c1x[k]; vy[k] = c1y[k]; }
#pragma unroll
        for (int k = 0; k < 4; k++) { vx[4 + k] = c2x[k]; vy[4 + k] = c2y[k]; }

        // ---- corners-in-box (division-free: norms are > 0) ----
        {
            float abx = c2x[1] - c2x[0], aby = c2y[1] - c2y[0];
            float adx = c2x[3] - c2x[0], ady = c2y[3] - c2y[0];
            float nab = abx * abx + aby * aby, nad = adx * adx + ady * ady;
            float eab = 1e-6f * nab, ead = 1e-6f * nad;
#pragma unroll
            for (int k = 0; k < 4; k++) {
                float amx = c1x[k] - c2x[0], amy = c1y[k] - c2y[0];
                float pab = abx * amx + aby * amy;
                float pad = adx * amx + ady * amy;
                bool c = (pab > -eab) && (pab < nab + eab) &&
                         (pad > -ead) && (pad < nad + ead);
                vm |= ((unsigned)c) << k;
            }
        }
        {
            float abx = c1x[1] - c1x[0], aby = c1y[1] - c1y[0];
            float adx = c1x[3] - c1x[0], ady = c1y[3] - c1y[0];
            float nab = abx * abx + aby * aby, nad = adx * adx + ady * ady;
            float eab = 1e-6f * nab, ead = 1e-6f * nad;
#pragma unroll
            for (int k = 0; k < 4; k++) {
                float amx = c2x[k] - c1x[0], amy = c2y[k] - c1y[0];
                float pab = abx * amx + aby * amy;
                float pad = adx * amx + ady * amy;
                bool c = (pab > -eab) && (pab < nab + eab) &&
                         (pad > -ead) && (pad < nad + ead);
                vm |= ((unsigned)c) << (4 + k);
            }
        }

        // ---- 16 edge-edge intersections (rcp instead of div; num==0 -> inf/nan -> mask false) ----
#pragma unroll
        for (int e1 = 0; e1 < 4; e1++) {
            float x1 = c1x[e1], y1 = c1y[e1];
            float e1xv = c1x[(e1 + 1) & 3] - x1, e1yv = c1y[(e1 + 1) & 3] - y1;
#pragma unroll
            for (int e2 = 0; e2 < 4; e2++) {
                float x3 = c2x[e2], y3 = c2y[e2];
                float e2xv = c2x[(e2 + 1) & 3] - x3, e2yv = c2y[(e2 + 1) & 3] - y3;
                float num = e2yv * e1xv - e2xv * e1yv;
                float dx = x1 - x3, dy = y1 - y3;
                float den_t = e2xv * dy - e2yv * dx;
                float den_u = e1xv * dy - e1yv * dx;
                float r = prcp(num);
                float tt = den_t * r;
                float uu = -den_u * r;
                bool mk = (tt > 0.0f) && (tt < 1.0f) && (uu > 0.0f) && (uu < 1.0f);
                int idx = 8 + e1 * 4 + e2;
                vx[idx] = mk ? x1 + tt * e1xv : 0.0f;
                vy[idx] = mk ? y1 + tt * e1yv : 0.0f;
                vm |= ((unsigned)mk) << idx;
            }
        }

        // ---- centroid of valid vertices ----
        float sx = 0.0f, sy = 0.0f;
        int nv = __popc(vm);
#pragma unroll
        for (int k = 0; k < 24; k++) {
            bool v = (vm >> k) & 1u;
            sx += v ? vx[k] : 0.0f;
            sy += v ? vy[k] : 0.0f;
        }
        float den = fmaxf((float)nv, 1.0f);
        float r0 = prcp(den);
        float mx = sx * r0, my = sy * r0;

        // ---- sort keys: monotone pseudo-angle (order-equivalent to atan2) ----
        float ka[24], rx[24], ry[24];
#pragma unroll
        for (int k = 0; k < 24; k++) {
            float x = vx[k] - mx, y = vy[k] - my;
            rx[k] = x; ry[k] = y;
            float d = fabsf(x) + fabsf(y);
            float q = 1.0f - x * prcp(d);
            float pa = copysignf(q, y);
            pa = (d == 0.0f) ? 0.0f : pa;
            bool v = (vm >> k) & 1u;
            ka[k] = v ? pa : 1e6f;
        }

        // ---- Batcher odd-even mergesort network, n=24 (132 CEs), branchless ----
#define CE(A, B) do { \
        bool sw = ka[B] < ka[A]; \
        float ta = sw ? ka[B] : ka[A]; float tb = sw ? ka[A] : ka[B]; ka[A] = ta; ka[B] = tb; \
        ta = sw ? rx[B] : rx[A]; tb = sw ? rx[A] : rx[B]; rx[A] = ta; rx[B] = tb; \
        ta = sw ? ry[B] : ry[A]; tb = sw ? ry[A] : ry[B]; ry[A] = ta; ry[B] = tb; \
    } while (0)

        // p=1
        CE(0,1); CE(2,3); CE(4,5); CE(6,7); CE(8,9); CE(10,11); CE(12,13); CE(14,15); CE(16,17); CE(18,19); CE(20,21); CE(22,23);
        // p=2
        CE(0,2); CE(1,3); CE(4,6); CE(5,7); CE(8,10); CE(9,11); CE(12,14); CE(13,15); CE(16,18); CE(17,19); CE(20,22); CE(21,23);
        CE(1,2); CE(5,6); CE(9,10); CE(13,14); CE(17,18); CE(21,22);
        // p=4
        CE(0,4); CE(1,5); CE(2,6); CE(3,7); CE(8,12); CE(9,13); CE(10,14); CE(11,15); CE(16,20); CE(17,21); CE(18,22); CE(19,23);
        CE(2,4); CE(3,5); CE(10,12); CE(11,13); CE(18,20); CE(19,21);
        CE(1,2); CE(3,4); CE(5,6); CE(9,10); CE(11,12); CE(13,14); CE(17,18); CE(19,20); CE(21,22);
        // p=8
        CE(0,8); CE(1,9); CE(2,10); CE(3,11); CE(4,12); CE(5,13); CE(6,14); CE(7,15);
        CE(4,8); CE(5,9); CE(6,10); CE(7,11);
        CE(2,4); CE(3,5); CE(6,8); CE(7,9); CE(10,12); CE(11,13); CE(18,20); CE(19,21);
        CE(1,2); CE(3,4); CE(5,6); CE(7,8); CE(9,10); CE(11,12); CE(13,14); CE(17,18); CE(19,20); CE(21,22);
        // p=16
        CE(0,16); CE(1,17); CE(2,18); CE(3,19); CE(4,20); CE(5,21); CE(6,22); CE(7,23);
        CE(8,16); CE(9,17); CE(10,18); CE(11,19); CE(12,20); CE(13,21); CE(14,22); CE(15,23);
        CE(4,8); CE(5,9); CE(6,10); CE(7,11); CE(12,16); CE(13,17); CE(14,18); CE(15,19);
        CE(2,4); CE(3,5); CE(6,8); CE(7,9); CE(10,12); CE(11,13); CE(14,16); CE(15,17); CE(18,20); CE(19,21);
        CE(1,2); CE(3,4); CE(5,6); CE(7,8); CE(9,10); CE(11,12); CE(13,14); CE(15,16); CE(17,18); CE(19,20); CE(21,22);
#undef CE

        // ---- shoelace over the first nv sorted vertices (rel coords; telescoping-equivalent) ----
        float area2 = 0.0f;
#pragma unroll
        for (int i = 0; i + 1 < 24; i++) {
            float c = rx[i] * ry[i + 1] - rx[i + 1] * ry[i];
            area2 += (i + 1 < nv) ? c : 0.0f;
        }
        float lx = rx[0], ly = ry[0];
#pragma unroll
        for (int i = 1; i < 24; i++) {
            bool c = i < nv;
            lx = c ? rx[i] : lx;
            ly = c ? ry[i] : ly;
        }
        area2 += lx * ry[0] - rx[0] * ly;
        float inter2d = 0.5f * fabsf(area2);

        // ---- z overlap, volumes, iou ----
        float zmax1 = p[2] + p[5] * 0.5f, zmin1 = p[2] - p[5] * 0.5f;
        float zmax2 = t[2] + t[5] * 0.5f, zmin2 = t[2] - t[5] * 0.5f;
        float zov = fmaxf(fminf(zmax1, zmax2) - fmaxf(zmin1, zmin2), 0.0f);
        float inter3d = inter2d * zov;
        float v1 = p[3] * p[4] * p[5];
        float v2 = t[3] * t[4] * t[5];
        float uni = v1 + v2 - inter3d;
        float iou = inter3d / uni;
        loss = (1.0f - iou) * wgt[n];
    }

    // deterministic block reduction
#pragma unroll
    for (int off = 32; off > 0; off >>= 1) loss += __shfl_down(loss, off, 64);
    __shared__ float sm[THREADS / 64];
    int lane = threadIdx.x & 63, wv = threadIdx.x >> 6;
    if (lane == 0) sm[wv] = loss;
    __syncthreads();
    if (threadIdx.x == 0) {
        float s = 0.0f;
#pragma unroll
        for (int w = 0; w < THREADS / 64; w++) s += sm[w];
        partial[blockIdx.x] = s;
    }
}

__global__ void __launch_bounds__(256) reduce_kernel(const float* __restrict__ partial,
                                                     int nb, float* __restrict__ out, int N) {
    __shared__ float sm[256];
    float s = 0.0f;
    for (int i = threadIdx.x; i < nb; i += 256) s += partial[i];
    sm[threadIdx.x] = s;
    __syncthreads();
    for (int off = 128; off > 0; off >>= 1) {
        if (threadIdx.x < off) sm[threadIdx.x] += sm[threadIdx.x + off];
        __syncthreads();
    }
    if (threadIdx.x == 0) out[0] = sm[0] / (float)N;
}

extern "C" void kernel_launch(void* const* d_in, const int* in_sizes, int n_in,
                              void* d_out, int out_size, void* d_ws, size_t ws_size,
                              hipStream_t stream) {
    const float* pred = (const float*)d_in[0];
    const float* tgt  = (const float*)d_in[1];
    const float* wgt  = (const float*)d_in[2];
    int N = in_sizes[2];
    int nb = (N + THREADS - 1) / THREADS;
    float* partial = (float*)d_ws;
    iou3d_kernel<<<nb, THREADS, 0, stream>>>(pred, tgt, wgt, partial, N);
    reduce_kernel<<<1, 256, 0, stream>>>(partial, nb, (float*)d_out, N);
}